// Round 11
// baseline (23.663 us; speedup 1.0000x reference)
//
#include <hip/hip_runtime.h>
#include <hip/hip_bf16.h>

// Decompose: algebraically a single 5x5 conv with scalar taps
//   a_k = wS_k . wE_k  (k = i*5+j), bias = sum_k (wS_k . bE_k + bS_k)
//   out = clip( (sum_k a_k * xp[h+i, w+j] + bias) / 25, 0, 1 )
// over xp = reflect-pad(clip(x,0,1), 2). Shapes: x (4,3,1024,1024) fp32.
//
// R11 = R10 (TBH=16, rotating 5-row acc, PF=8, packed fp32, grid 768)
// + BRANCHLESS main loop. R10 spent ~950cyc/row-iter (= full HBM latency
// every row): the per-row divergent lt/rt/interior branch chopped the
// unrolled loop into 40 exec-masked regions, forcing conservative waitcnt
// and defeating the 8-deep load pipeline. The 3 cases are only a
// permutation of the 8 loaded floats: lt differs in r8[0,2,3], rt in
// r8[4,5,7] -> 6 cndmask selects with loop-invariant masks, zero branches.
// Bias folded into acc init (saves epilogue adds).

#define HH 1024
#define WW 1024
#define NIMG 12
#define TBH 16             // output rows per block
#define ROWS (TBH + 4)     // 20 input rows touched
#define PF 8               // rolling load-buffer depth (rows)

typedef float f32x4 __attribute__((ext_vector_type(4)));
typedef float f32x2 __attribute__((ext_vector_type(2)));

__device__ __forceinline__ float readlane_f(float v, int lane) {
    return __int_as_float(__builtin_amdgcn_readlane(__float_as_int(v), lane));
}

__device__ __forceinline__ float sgpr_bcast(float v) {
    return __int_as_float(__builtin_amdgcn_readfirstlane(__float_as_int(v)));
}

__device__ __forceinline__ float dot4(f32x4 a, f32x4 b) {
    return a.x * b.x + a.y * b.y + a.z * b.z + a.w * b.w;
}

__device__ __forceinline__ f32x4 clip01v4(f32x4 v) {
    f32x4 z = {0.f, 0.f, 0.f, 0.f};
    f32x4 o = {1.f, 1.f, 1.f, 1.f};
    return __builtin_elementwise_min(__builtin_elementwise_max(v, z), o);
}

__device__ __forceinline__ f32x2 clip01v2(f32x2 v) {
    f32x2 z = {0.f, 0.f};
    f32x2 o = {1.f, 1.f};
    return __builtin_elementwise_min(__builtin_elementwise_max(v, z), o);
}

__global__ __launch_bounds__(256) void conv5_kernel(const float* __restrict__ x,
                                                    const float* __restrict__ wE,
                                                    const float* __restrict__ bE,
                                                    const float* __restrict__ wS,
                                                    const float* __restrict__ bS,
                                                    float* __restrict__ out) {
    int lane = threadIdx.x & 63;

    // ---- Lane-parallel constant prep (per wave, redundant; ~300 cyc) ----
    float apass[2], cacc = 0.f;
    #pragma unroll
    for (int p = 0; p < 2; ++p) {
        int k = p * 16 + (lane >> 2);
        float a = 0.f;
        if (k < 25) {
            int base = k * 64 + (lane & 3) * 16;
            #pragma unroll
            for (int i = 0; i < 4; ++i) {
                f32x4 sv = *(const f32x4*)(wS + base + 4 * i);
                f32x4 ev = *(const f32x4*)(wE + base + 4 * i);
                f32x4 bv = *(const f32x4*)(bE + base + 4 * i);
                a += dot4(sv, ev);
                cacc += dot4(sv, bv);
            }
        }
        a += __shfl_xor(a, 1);
        a += __shfl_xor(a, 2);     // all 4 lanes of the group hold a_k
        apass[p] = a;
    }
    if (lane < 25) cacc += bS[lane];
    #pragma unroll
    for (int off = 32; off; off >>= 1) cacc += __shfl_xor(cacc, off);
    float bias = sgpr_bcast(cacc * (1.f / 25.f));
    f32x2 bias2 = {bias, bias};

    float wv[25];
    #pragma unroll
    for (int k = 0; k < 16; ++k) wv[k] = readlane_f(apass[0], 4 * k) * (1.f / 25.f);
    #pragma unroll
    for (int k = 16; k < 25; ++k) wv[k] = readlane_f(apass[1], 4 * (k - 16)) * (1.f / 25.f);

    // ---- Tile mapping: XCD-aware bijective swizzle (768 % 8 == 0) ----
    int nwg = gridDim.x;
    int cpx = nwg >> 3;
    int l = (blockIdx.x & 7) * cpx + (blockIdx.x >> 3);
    int img = l >> 6;                         // 64 row-blocks per image
    int rb = l & 63;
    int row0 = rb * TBH;

    const float* src = x + (size_t)img * (HH * WW);
    int tid = threadIdx.x;
    int cbase = tid * 4;                      // output col base

    // Column window: source cols cbase-2 .. cbase+5 (reflect at edges).
    bool lt = (cbase == 0);
    bool rt = (cbase == 1020);
    int qa = lt ? 0 : cbase - 2;
    int qb = rt ? 1020 : cbase + 2;

    // Row pointer with vertical reflection (block-uniform scalar math).
    auto rowptr = [&](int ir) -> const float* {
        int prow = row0 - 2 + ir;
        int sr = prow < 0 ? -prow : (prow >= HH ? 2 * HH - 2 - prow : prow);
        return src + (size_t)sr * WW;
    };

    // ---- Rolling structures ----
    f32x4 bufA[PF], bufB[PF];        // load pipeline, depth 8 rows
    f32x2 acc[5][2];                 // rotating output-row accumulators (packed)

    #pragma unroll
    for (int ir = 0; ir < PF; ++ir) {
        const float* rp = rowptr(ir);
        bufA[ir] = *(const f32x4*)(rp + qa);
        bufB[ir] = *(const f32x4*)(rp + qb);
    }
    __builtin_amdgcn_sched_barrier(0);   // keep prologue loads hoisted

    float* op = out + (size_t)img * (HH * WW) + (size_t)row0 * WW + cbase;

    #pragma unroll
    for (int ir = 0; ir < ROWS; ++ir) {
        f32x4 A = bufA[ir & (PF - 1)];
        f32x4 B = bufB[ir & (PF - 1)];
        if (ir + PF < ROWS) {
            const float* rp = rowptr(ir + PF);
            bufA[ir & (PF - 1)] = *(const f32x4*)(rp + qa);
            bufB[ir & (PF - 1)] = *(const f32x4*)(rp + qb);
        }

        // Packed clip (window selection below permutes clipped values).
        A = clip01v4(A);
        B = clip01v4(B);

        // BRANCHLESS window extraction: interior pattern + 6 cndmask
        // overrides with loop-invariant lt/rt masks.
        float r8[8] = {A.x, A.y, A.z, A.w, B.x, B.y, B.z, B.w};
        r8[0] = lt ? A.z : r8[0];
        r8[2] = lt ? A.x : r8[2];
        r8[3] = lt ? A.y : r8[3];
        r8[4] = rt ? B.z : r8[4];
        r8[5] = rt ? B.w : r8[5];
        r8[7] = rt ? B.y : r8[7];

        // Sliding pairs: pr[j] = {r8[j], r8[j+1]}, j = 0..6.
        f32x2 pr[7];
        #pragma unroll
        for (int j = 0; j < 7; ++j) { pr[j].x = r8[j]; pr[j].y = r8[j + 1]; }

        // Output row ir starts here: init its rotating slot with the bias
        // (folds the epilogue bias-add into the accumulation).
        if (ir < TBH) {
            acc[ir % 5][0] = bias2;
            acc[ir % 5][1] = bias2;
        }

        // Input row ir contributes to output rows ir-4 .. ir (packed FMA).
        #pragma unroll
        for (int dr = 0; dr < 5; ++dr) {
            int orow = ir - dr;
            if (orow < 0 || orow >= TBH) continue;
            #pragma unroll
            for (int j = 0; j < 5; ++j) {
                float wj = wv[dr * 5 + j];
                f32x2 w2 = {wj, wj};
                acc[orow % 5][0] += pr[j] * w2;       // cols 0,1
                acc[orow % 5][1] += pr[j + 2] * w2;   // cols 2,3
            }
        }

        // Output row ir-4 is final: packed clip, NT store.
        if (ir >= 4) {
            int orow = ir - 4;
            f32x2 lo = clip01v2(acc[orow % 5][0]);
            f32x2 hi = clip01v2(acc[orow % 5][1]);
            f32x4 o = {lo.x, lo.y, hi.x, hi.y};
            __builtin_nontemporal_store(o, (f32x4*)(op + (size_t)orow * WW));
        }
    }
}

extern "C" void kernel_launch(void* const* d_in, const int* in_sizes, int n_in,
                              void* d_out, int out_size, void* d_ws, size_t ws_size,
                              hipStream_t stream) {
    const float* x  = (const float*)d_in[0];
    const float* wE = (const float*)d_in[1];
    const float* bE = (const float*)d_in[2];
    const float* wS = (const float*)d_in[3];
    const float* bS = (const float*)d_in[4];
    float* out = (float*)d_out;

    int nblocks = NIMG * (HH / TBH);   // 12 * 64 = 768
    conv5_kernel<<<nblocks, 256, 0, stream>>>(x, wE, bE, wS, bS, out);
}